// Round 9
// baseline (687.895 us; speedup 1.0000x reference)
//
#include <hip/hip_runtime.h>

#define K_CODES 1024
#define DIM 128
#define HW 1024
#define NTOT 65536
#define DECAY 0.99f
#define OMD 0.01f
#define EPS 1e-5f
#define CCOEF 0.25f
#define MARGIN 4e-4f

// d_out offsets (floats)
#define OFF_Q    0
#define OFF_IDX  8388608
#define OFF_LOSS (8388608 + 65536)
#define OFF_EMB  (OFF_LOSS + 1)
#define OFF_ECS  (OFF_EMB + 131072)
#define OFF_EMAW (OFF_ECS + 1024)

typedef __attribute__((ext_vector_type(8))) short short8v;
typedef __attribute__((ext_vector_type(4))) float f32x4;

__device__ __forceinline__ unsigned short f2bf(float f) {
    unsigned u = __float_as_uint(f);
    u += 0x7fffu + ((u >> 16) & 1u);      // RNE to bf16 (inputs finite)
    return (unsigned short)(u >> 16);
}
__device__ __forceinline__ float bf2f(unsigned short h) {
    return __uint_as_float(((unsigned)h) << 16);
}

__global__ __launch_bounds__(256) void kzero(float* __restrict__ p, int n) {
    int i = blockIdx.x * 256 + threadIdx.x;
    if (i < n) p[i] = 0.f;
}

// numpy pairwise_sum replica (contiguous fp32, n=128, SSE nlanes=4) — verified.
__device__ __forceinline__ float np_pairwise_sumsq_128(const float* p, size_t stride) {
    float r[8][4];
    #pragma unroll
    for (int j = 0; j < 8; ++j)
        #pragma unroll
        for (int L = 0; L < 4; ++L) {
            float x = p[(size_t)(j * 4 + L) * stride];
            r[j][L] = __fmul_rn(x, x);
        }
    #pragma unroll
    for (int c = 1; c < 4; ++c)
        #pragma unroll
        for (int j = 0; j < 8; ++j)
            #pragma unroll
            for (int L = 0; L < 4; ++L) {
                float x = p[(size_t)(c * 32 + j * 4 + L) * stride];
                r[j][L] = __fadd_rn(r[j][L], __fmul_rn(x, x));
            }
    float V[4];
    #pragma unroll
    for (int L = 0; L < 4; ++L) {
        float a = __fadd_rn(r[0][L], r[1][L]);
        float b = __fadd_rn(r[2][L], r[3][L]);
        float c2 = __fadd_rn(r[4][L], r[5][L]);
        float d2 = __fadd_rn(r[6][L], r[7][L]);
        V[L] = __fadd_rn(__fadd_rn(a, b), __fadd_rn(c2, d2));
    }
    return __fadd_rn(__fadd_rn(V[0], V[1]), __fadd_rn(V[2], V[3]));
}

// LDS-transpose 128 rows of ze -> flat_c (coalesced) + nx per row (verified).
__global__ __launch_bounds__(256) void knx(const float* __restrict__ ze,
                                           float* __restrict__ nx,
                                           float* __restrict__ flat_c) {
    __shared__ float t[128][133];
    const int tid = threadIdx.x;
    const int n0 = blockIdx.x * 128;
    const int b = n0 >> 10, hw0 = n0 & (HW - 1);
    const float* zb = ze + (size_t)b * (DIM * HW) + hw0;
    #pragma unroll
    for (int i = 0; i < 64; ++i) {
        int d = i * 2 + (tid >> 7);
        int hw = tid & 127;
        t[hw][d] = zb[(size_t)d * HW + hw];
    }
    __syncthreads();
    if (tid < 128) nx[n0 + tid] = np_pairwise_sumsq_128(&t[tid][0], 1);
    if (flat_c) {
        #pragma unroll
        for (int i = 0; i < 16; ++i) {
            int lin = i * 256 + tid;
            int r  = lin >> 5;
            int c4 = lin & 31;
            float4 v = *(const float4*)&t[r][c4 * 4];
            *(float4*)&flat_c[(size_t)(n0 + r) * DIM + c4 * 4] = v;
        }
    }
}

// ne[k] (np-pairwise, verified) + bf16 hi/lo split of embed
__global__ __launch_bounds__(256) void knorm(const float* __restrict__ embed,
                                             float* __restrict__ norm2,
                                             unsigned short* __restrict__ eh_g,
                                             unsigned short* __restrict__ el_g) {
    int k = blockIdx.x * 256 + threadIdx.x;
    const float* row = embed + (size_t)k * DIM;
    norm2[k] = np_pairwise_sumsq_128(row, 1);
    if (eh_g) {
        #pragma unroll 8
        for (int d = 0; d < DIM; ++d) {
            float f = row[d];
            unsigned short h = f2bf(f);
            eh_g[(size_t)k * DIM + d] = h;
            el_g[(size_t)k * DIM + d] = f2bf(f - bf2f(h));
        }
    }
}

// bf16x3 MFMA single-pass argmin v3. Block: 128 rows x 1024 codes, 4 waves.
// 16 iterations x 64 codes (4 subtiles of 16); 96 MFMA + 32 ds_read_b128 per
// wave per barrier. Per row tracks (min1, code1, min2). If min2-min1 > MARGIN
// the exact fp32-pipeline winner is provably code1 (approx skew <= 6.2e-5):
// write idx directly. Else append row to flagged list for krefine's exact
// full scan (also captures all exact ties).
// LDS XOR-swizzle (verified r8): granule g of code c at c*128+((g^(c&15))*8).
__global__ __launch_bounds__(256, 2) void kapprox(
    const float* __restrict__ flat_c, const unsigned short* __restrict__ eh_g,
    const unsigned short* __restrict__ el_g, const float* __restrict__ norm2,
    int* __restrict__ idx_ws, float* __restrict__ idx_out,
    unsigned* __restrict__ hist, unsigned* __restrict__ flcnt,
    unsigned* __restrict__ fl_list)
{
    __shared__ __align__(16) unsigned short ehs[2][64 * 128];
    __shared__ __align__(16) unsigned short els[2][64 * 128];
    __shared__ float nes[1024];

    const int tid = threadIdx.x;
    const int l = tid & 63;
    const int w = tid >> 6;
    const int lg = l >> 4;        // 0..3
    const int lm = l & 15;
    const int n0 = blockIdx.x * 128;

    for (int i = tid; i < 1024; i += 256) nes[i] = norm2[i];

    // x-frags: rows n0 + w*32 + lm (group0) / +16 (group1); k = ks*32+lg*8+e
    short8v xh0[4], xl0[4], xh1[4], xl1[4];
    {
        const float* xr0 = flat_c + (size_t)(n0 + w * 32 + lm) * DIM;
        const float* xr1 = xr0 + 16 * DIM;
        #pragma unroll
        for (int ks = 0; ks < 4; ++ks) {
            int kb = ks * 32 + lg * 8;
            float f0[8], f1[8];
            *(float4*)&f0[0] = *(const float4*)(xr0 + kb);
            *(float4*)&f0[4] = *(const float4*)(xr0 + kb + 4);
            *(float4*)&f1[0] = *(const float4*)(xr1 + kb);
            *(float4*)&f1[4] = *(const float4*)(xr1 + kb + 4);
            #pragma unroll
            for (int e = 0; e < 8; ++e) {
                unsigned short h0 = f2bf(f0[e]);
                unsigned short h1 = f2bf(f1[e]);
                xh0[ks][e] = (short)h0;
                xl0[ks][e] = (short)f2bf(f0[e] - bf2f(h0));
                xh1[ks][e] = (short)h1;
                xl1[ks][e] = (short)f2bf(f1[e] - bf2f(h1));
            }
        }
    }

    // staging: 4 slots/array/thread; slot j -> code (tid>>4)+j*16, granule tid&15
    const int cc = tid >> 4;
    const int g0 = tid & 15;
    int soff[4];
    size_t gsrc[4];
    #pragma unroll
    for (int j = 0; j < 4; ++j) {
        int c = cc + j * 16;
        soff[j] = c * 128 + ((g0 ^ (c & 15)) * 8);
        gsrc[j] = (size_t)c * 128 + g0 * 8;
    }

    uint4 ph[4], pl[4];
    #pragma unroll
    for (int j = 0; j < 4; ++j) {
        ph[j] = *(const uint4*)(eh_g + gsrc[j]);
        pl[j] = *(const uint4*)(el_g + gsrc[j]);
    }
    #pragma unroll
    for (int j = 0; j < 4; ++j) {
        *(uint4*)&ehs[0][soff[j]] = ph[j];
        *(uint4*)&els[0][soff[j]] = pl[j];
    }
    __syncthreads();

    float m1_0 = 3.4e38f, m2_0 = 3.4e38f;
    float m1_1 = 3.4e38f, m2_1 = 3.4e38f;
    int c1_0 = 0, c1_1 = 0;

    for (int it = 0; it < 16; ++it) {
        const int buf = it & 1;
        const int nt = it + 1;
        if (nt < 16) {
            const size_t nb = (size_t)nt * 8192;
            #pragma unroll
            for (int j = 0; j < 4; ++j) {
                ph[j] = *(const uint4*)(eh_g + nb + gsrc[j]);
                pl[j] = *(const uint4*)(el_g + nb + gsrc[j]);
            }
        }
        #pragma unroll
        for (int sub = 0; sub < 4; ++sub) {
            f32x4 a0 = {0.f,0.f,0.f,0.f}, a1 = {0.f,0.f,0.f,0.f};
            #pragma unroll
            for (int ks = 0; ks < 4; ++ks) {
                int off = sub * 2048 + lm * 128 + (((ks * 4 + lg) ^ lm) * 8);
                short8v e8 = *(const short8v*)(&ehs[buf][off]);
                short8v l8 = *(const short8v*)(&els[buf][off]);
                a0 = __builtin_amdgcn_mfma_f32_16x16x32_bf16(e8, xh0[ks], a0, 0, 0, 0);
                a0 = __builtin_amdgcn_mfma_f32_16x16x32_bf16(l8, xh0[ks], a0, 0, 0, 0);
                a0 = __builtin_amdgcn_mfma_f32_16x16x32_bf16(e8, xl0[ks], a0, 0, 0, 0);
                a1 = __builtin_amdgcn_mfma_f32_16x16x32_bf16(e8, xh1[ks], a1, 0, 0, 0);
                a1 = __builtin_amdgcn_mfma_f32_16x16x32_bf16(l8, xh1[ks], a1, 0, 0, 0);
                a1 = __builtin_amdgcn_mfma_f32_16x16x32_bf16(e8, xl1[ks], a1, 0, 0, 0);
            }
            #pragma unroll
            for (int r = 0; r < 4; ++r) {
                int code = it * 64 + sub * 16 + lg * 4 + r;
                float ne = nes[code];
                float s0 = ne - 2.f * a0[r];
                float s1 = ne - 2.f * a1[r];
                m2_0 = fminf(m2_0, fmaxf(m1_0, s0));
                if (s0 < m1_0) { m1_0 = s0; c1_0 = code; }
                m2_1 = fminf(m2_1, fmaxf(m1_1, s1));
                if (s1 < m1_1) { m1_1 = s1; c1_1 = code; }
            }
        }
        if (nt < 16) {
            #pragma unroll
            for (int j = 0; j < 4; ++j) {
                *(uint4*)&ehs[buf ^ 1][soff[j]] = ph[j];
                *(uint4*)&els[buf ^ 1][soff[j]] = pl[j];
            }
        }
        __syncthreads();
    }

    // merge (m1,c1,m2) across the 4 lg lanes (xor 16, then 32)
    #pragma unroll
    for (int mk = 16; mk <= 32; mk <<= 1) {
        float om1 = __shfl_xor(m1_0, mk, 64);
        int   oc1 = __shfl_xor(c1_0, mk, 64);
        float om2 = __shfl_xor(m2_0, mk, 64);
        m2_0 = fminf(fminf(m2_0, om2), fmaxf(m1_0, om1));
        if (om1 < m1_0 || (om1 == m1_0 && oc1 < c1_0)) { m1_0 = om1; c1_0 = oc1; }
        float pm1 = __shfl_xor(m1_1, mk, 64);
        int   pc1 = __shfl_xor(c1_1, mk, 64);
        float pm2 = __shfl_xor(m2_1, mk, 64);
        m2_1 = fminf(fminf(m2_1, pm2), fmaxf(m1_1, pm1));
        if (pm1 < m1_1 || (pm1 == m1_1 && pc1 < c1_1)) { m1_1 = pm1; c1_1 = pc1; }
    }
    if (lg == 0) {
        int n = n0 + w * 32 + lm;
        if (m2_0 - m1_0 > MARGIN) {
            idx_ws[n] = c1_0;
            idx_out[n] = (float)c1_0;
            atomicAdd(&hist[c1_0], 1u);
        } else {
            unsigned p = atomicAdd(flcnt, 1u);
            fl_list[p] = (unsigned)n;
        }
        n += 16;
        if (m2_1 - m1_1 > MARGIN) {
            idx_ws[n] = c1_1;
            idx_out[n] = (float)c1_1;
            atomicAdd(&hist[c1_1], 1u);
        } else {
            unsigned p = atomicAdd(flcnt, 1u);
            fl_list[p] = (unsigned)n;
        }
    }
}

// exact full-scan for flagged rows: 16 rows/block, x staged in LDS.
// Semantics identical to verified kargmin: ascending-d fmaf chain,
// s = fsub(fadd(nx,ne), fmul(2,dot)), strict <, lowest k on ties.
__global__ __launch_bounds__(256) void krefine(
    const float* __restrict__ flat_c, const float* __restrict__ embed,
    const float* __restrict__ norm2, const float* __restrict__ nxg,
    const unsigned* __restrict__ flcnt, const unsigned* __restrict__ fl_list,
    int* __restrict__ idx_ws, float* __restrict__ idx_out,
    unsigned* __restrict__ hist)
{
    __shared__ float xrow[16][132];
    __shared__ float xnx[16];
    __shared__ int   rn[16];
    const int tid = threadIdx.x;
    const unsigned nflag = flcnt[0];
    for (unsigned base = blockIdx.x * 16u; base < nflag; base += gridDim.x * 16u) {
        __syncthreads();   // protect LDS from previous batch readers
        if (tid < 16) {
            unsigned f = base + tid;
            int n = (f < nflag) ? (int)fl_list[f] : -1;
            rn[tid] = n;
            xnx[tid] = (n >= 0) ? nxg[n] : 0.f;
        }
        __syncthreads();
        #pragma unroll
        for (int j = 0; j < 8; ++j) {
            int slot = j * 256 + tid;
            int r = slot >> 7, d = slot & 127;
            int n = rn[r];
            if (n >= 0) xrow[r][d] = flat_c[(size_t)n * DIM + d];
        }
        __syncthreads();
        const int row = tid >> 4;
        const int q = tid & 15;
        const int n = rn[row];
        float bs = 3.4e38f;
        int bk = 1 << 30;
        if (n >= 0) {
            const float* xr = &xrow[row][0];
            const float nx = xnx[row];
            #pragma unroll 2
            for (int m = 0; m < 64; ++m) {
                int k = q + m * 16;
                const float* er = embed + (size_t)k * DIM;
                float dot = 0.f;
                #pragma unroll
                for (int d4 = 0; d4 < 32; ++d4) {
                    float4 e4 = *(const float4*)(er + d4 * 4);
                    float4 x4 = *(const float4*)(xr + d4 * 4);
                    dot = fmaf(x4.x, e4.x, dot);
                    dot = fmaf(x4.y, e4.y, dot);
                    dot = fmaf(x4.z, e4.z, dot);
                    dot = fmaf(x4.w, e4.w, dot);
                }
                float s = __fsub_rn(__fadd_rn(nx, norm2[k]), __fmul_rn(2.f, dot));
                if (s < bs || (s == bs && k < bk)) { bs = s; bk = k; }
            }
        }
        #pragma unroll
        for (int off = 8; off >= 1; off >>= 1) {
            float os = __shfl_xor(bs, off, 16);
            int   ok = __shfl_xor(bk, off, 16);
            if (os < bs || (os == bs && ok < bk)) { bs = os; bk = ok; }
        }
        if (q == 0 && n >= 0) {
            idx_ws[n] = bk;
            idx_out[n] = (float)bk;
            atomicAdd(&hist[bk], 1u);
        }
    }
}

// ---- fallback exact-GEMM argmin (verified path, used when ws too small) ----
__global__ __launch_bounds__(256, 2) void kargmin(
    const float* __restrict__ ze, const float* __restrict__ embed,
    const float* __restrict__ norm2, const float* __restrict__ nxg,
    int* __restrict__ idx_ws, float* __restrict__ idx_out,
    unsigned int* __restrict__ hist)
{
    __shared__ float xs[128 * 36];
    __shared__ float es[128 * 36];
    __shared__ float nxs[128];
    const int tid = threadIdx.x;
    const int tx = tid & 15, ty = tid >> 4;
    const int n0 = blockIdx.x * 128;
    const float* zbase = ze + (size_t)(n0 >> 10) * (DIM * HW) + (n0 & (HW - 1));
    if (tid < 128) nxs[tid] = nxg[n0 + tid];
    float minv[8];
    int   mini[8];
    #pragma unroll
    for (int i = 0; i < 8; ++i) { minv[i] = 3.4e38f; mini[i] = 0; }
    for (int kt = 0; kt < 8; ++kt) {
        float acc[8][8];
        #pragma unroll
        for (int i = 0; i < 8; ++i)
            #pragma unroll
            for (int j = 0; j < 8; ++j) acc[i][j] = 0.f;
        for (int dc = 0; dc < 4; ++dc) {
            __syncthreads();
            #pragma unroll
            for (int it = 0; it < 4; ++it) {
                int lin = it * 256 + tid;
                int r  = lin & 127;
                int gu = lin >> 7;
                const float* gp = zbase + (size_t)(dc * 32 + gu * 4) * HW + r;
                float4 v;
                v.x = gp[0]; v.y = gp[HW]; v.z = gp[2 * HW]; v.w = gp[3 * HW];
                *(float4*)&xs[r * 36 + gu * 4] = v;
            }
            #pragma unroll
            for (int it = 0; it < 4; ++it) {
                int lin = it * 256 + tid;
                int k  = lin >> 3;
                int gu = lin & 7;
                float4 v = *(const float4*)(embed + (size_t)(kt * 128 + k) * DIM + dc * 32 + gu * 4);
                *(float4*)&es[k * 36 + gu * 4] = v;
            }
            __syncthreads();
            #pragma unroll
            for (int g = 0; g < 8; ++g) {
                float4 xf[8];
                #pragma unroll
                for (int i = 0; i < 8; ++i)
                    xf[i] = *(const float4*)&xs[(ty + i * 16) * 36 + g * 4];
                #pragma unroll
                for (int j = 0; j < 8; ++j) {
                    float4 ef = *(const float4*)&es[(tx + j * 16) * 36 + g * 4];
                    #pragma unroll
                    for (int i = 0; i < 8; ++i) {
                        acc[i][j] = fmaf(xf[i].x, ef.x, acc[i][j]);
                        acc[i][j] = fmaf(xf[i].y, ef.y, acc[i][j]);
                        acc[i][j] = fmaf(xf[i].z, ef.z, acc[i][j]);
                        acc[i][j] = fmaf(xf[i].w, ef.w, acc[i][j]);
                    }
                }
            }
        }
        #pragma unroll
        for (int j = 0; j < 8; ++j) {
            int kg = kt * 128 + tx + j * 16;
            float nrm = norm2[kg];
            #pragma unroll
            for (int i = 0; i < 8; ++i) {
                float q = __fadd_rn(nxs[ty + i * 16], nrm);
                float t = __fmul_rn(2.f, acc[i][j]);
                float s = __fsub_rn(q, t);
                if (s < minv[i]) { minv[i] = s; mini[i] = kg; }
            }
        }
    }
    #pragma unroll
    for (int i = 0; i < 8; ++i) {
        float v = minv[i]; int ix = mini[i];
        #pragma unroll
        for (int off = 8; off >= 1; off >>= 1) {
            float v2 = __shfl_xor(v, off, 16);
            int   i2 = __shfl_xor(ix, off, 16);
            if (v2 < v || (v2 == v && i2 < ix)) { v = v2; ix = i2; }
        }
        if (tx == 0) {
            int n = n0 + ty + i * 16;
            idx_ws[n] = ix;
            idx_out[n] = (float)ix;
            atomicAdd(&hist[ix], 1u);
        }
    }
}

// gather quantized, transposed write, loss (+ optional atomic dw fallback)
__global__ __launch_bounds__(256) void kquant(
    const float* __restrict__ ze, const float* __restrict__ embed,
    const int* __restrict__ idx_ws, float* __restrict__ qout,
    float* __restrict__ dw_atomic, float* __restrict__ loss_acc)
{
    __shared__ float q[128 * 133];
    __shared__ int idxs[128];
    __shared__ float lsum[4];
    const int tid = threadIdx.x;
    const int n0 = blockIdx.x * 128;
    const int b = n0 >> 10;
    const int hw0 = n0 & (HW - 1);
    if (tid < 128) idxs[tid] = idx_ws[n0 + tid];
    __syncthreads();
    #pragma unroll
    for (int it = 0; it < 16; ++it) {
        int r = it * 8 + (tid >> 5);
        int c = tid & 31;
        float4 v = *(const float4*)(embed + (size_t)idxs[r] * DIM + c * 4);
        *(float4*)&q[r * 133 + c * 4] = v;
    }
    __syncthreads();
    const float* zb = ze + (size_t)b * (DIM * HW) + hw0;
    float* qb = qout + (size_t)b * (DIM * HW) + hw0;
    float lacc = 0.f;
    for (int dd = 0; dd < 64; ++dd) {
        int d = dd * 2 + (tid >> 7);
        int hw = tid & 127;
        float val = q[hw * 133 + d];
        size_t off = (size_t)d * HW + hw;
        float z = zb[off];
        qb[off] = val;
        float diff = val - z;
        lacc = fmaf(diff, diff, lacc);
        if (dw_atomic) atomicAdd(&dw_atomic[idxs[hw] * DIM + d], z);
    }
    #pragma unroll
    for (int off = 32; off >= 1; off >>= 1) lacc += __shfl_xor(lacc, off, 64);
    if ((tid & 63) == 0) lsum[tid >> 6] = lacc;
    __syncthreads();
    if (tid == 0) atomicAdd(loss_acc, lsum[0] + lsum[1] + lsum[2] + lsum[3]);
}

// deterministic segment-sum: block(8 waves)/code, waves scan n-ranges ascending
__global__ __launch_bounds__(512) void kdw(
    const int* __restrict__ idx_ws, const float* __restrict__ flat_c,
    float* __restrict__ dw)
{
    __shared__ float part[8][128];
    const int k = blockIdx.x;
    const int lane = threadIdx.x & 63;
    const int w = threadIdx.x >> 6;
    float lo = 0.f, hi = 0.f;
    const int nbeg = w * (NTOT / 8);
    const int nend = nbeg + (NTOT / 8);
    for (int base = nbeg; base < nend; base += 64) {
        int my = idx_ws[base + lane];
        unsigned long long m = __ballot(my == k);
        while (m) {
            int bit = __ffsll((long long)m) - 1;
            m &= m - 1;
            const float* row = flat_c + (size_t)(base + bit) * DIM;
            lo += row[lane];
            hi += row[lane + 64];
        }
    }
    part[w][lane] = lo;
    part[w][lane + 64] = hi;
    __syncthreads();
    if (w == 0) {
        float a = part[0][lane], b = part[0][lane + 64];
        #pragma unroll
        for (int u = 1; u < 8; ++u) {
            a += part[u][lane];
            b += part[u][lane + 64];
        }
        dw[k * DIM + lane] = a;
        dw[k * DIM + lane + 64] = b;
    }
}

__global__ __launch_bounds__(256) void kfin1(
    const unsigned int* __restrict__ hist, const float* __restrict__ ema_cs,
    float* __restrict__ out_ecs, float* __restrict__ rcp,
    float* __restrict__ loss_out, const float* __restrict__ loss_acc)
{
    const int tid = threadIdx.x;
    __shared__ float wsum[4];
    float local = 0.f;
    float necs[4];
    #pragma unroll
    for (int u = 0; u < 4; ++u) {
        int k = u * 256 + tid;
        necs[u] = DECAY * ema_cs[k] + OMD * (float)hist[k];
        out_ecs[k] = necs[u];
        local += necs[u];
    }
    #pragma unroll
    for (int off = 32; off >= 1; off >>= 1) local += __shfl_xor(local, off, 64);
    if ((tid & 63) == 0) wsum[tid >> 6] = local;
    __syncthreads();
    float ntot = wsum[0] + wsum[1] + wsum[2] + wsum[3];
    #pragma unroll
    for (int u = 0; u < 4; ++u) {
        int k = u * 256 + tid;
        float cs = (necs[u] + EPS) / (ntot + (float)K_CODES * EPS) * ntot;
        rcp[k] = 1.f / cs;
    }
    if (tid == 0) loss_out[0] = loss_acc[0] * (CCOEF / (float)((size_t)NTOT * DIM));
}

__global__ __launch_bounds__(256) void kfin2(
    const float* __restrict__ ema_w, const float* __restrict__ dw,
    const float* __restrict__ rcp, float* __restrict__ out_emb,
    float* __restrict__ out_emaw)
{
    int e = blockIdx.x * 256 + threadIdx.x;
    int k = e >> 7;
    float nw = DECAY * ema_w[e] + OMD * dw[e];
    out_emaw[e] = nw;
    out_emb[e] = nw * rcp[k];
}

extern "C" void kernel_launch(void* const* d_in, const int* in_sizes, int n_in,
                              void* d_out, int out_size, void* d_ws, size_t ws_size,
                              hipStream_t stream) {
    const float* ze     = (const float*)d_in[0];
    const float* embed  = (const float*)d_in[1];
    const float* ema_cs = (const float*)d_in[2];
    const float* ema_w  = (const float*)d_in[3];
    float* out = (float*)d_out;

    // ws layout (words), NO aliases (kapprox writes idx while eh still live):
    // hist/loss/flcnt/fl_list/dw contiguous so one kzero covers accumulators.
    float* ws = (float*)d_ws;
    float*          ws_norm2 = ws;                                   // 1024
    float*          ws_rcp   = ws + 1024;                            // 1024
    int*            ws_idx   = (int*)(ws + 2048);                    // 65536
    unsigned*       ws_hist  = (unsigned*)(ws + 67584);              // 1024
    float*          ws_loss  = ws + 68608;                           // 1
    unsigned*       ws_flcnt = (unsigned*)(ws + 68609);              // 1 (+2 pad)
    unsigned*       ws_fl    = (unsigned*)(ws + 68612);              // 65536
    float*          ws_dw    = ws + 134148;                          // 131072
    unsigned short* ws_eh    = (unsigned short*)(ws + 265220);       // 65536 words
    unsigned short* ws_el    = (unsigned short*)(ws + 330756);       // 65536 words
    float*          ws_nx    = ws + 396292;                          // 65536
    float*          ws_flat  = ws + 461828;                          // 8388608
    const size_t need = (size_t)8850436 * sizeof(float);
    const bool big_ws = ws_size >= need;

    if (big_ws) {
        // zero hist + loss + flcnt (contiguous 1026 words)
        hipLaunchKernelGGL(kzero, dim3(5), dim3(256), 0, stream, (float*)ws_hist, 1026);
        hipLaunchKernelGGL(knx, dim3(512), dim3(256), 0, stream, ze, ws_nx, ws_flat);
        hipLaunchKernelGGL(knorm, dim3(4), dim3(256), 0, stream, embed, ws_norm2, ws_eh, ws_el);
        hipLaunchKernelGGL(kapprox, dim3(512), dim3(256), 0, stream,
                           ws_flat, ws_eh, ws_el, ws_norm2,
                           ws_idx, out + OFF_IDX, ws_hist, ws_flcnt, ws_fl);
        hipLaunchKernelGGL(krefine, dim3(256), dim3(256), 0, stream,
                           ws_flat, embed, ws_norm2, ws_nx, ws_flcnt, ws_fl,
                           ws_idx, out + OFF_IDX, ws_hist);
        hipLaunchKernelGGL(kquant, dim3(512), dim3(256), 0, stream,
                           ze, embed, ws_idx, out + OFF_Q, (float*)nullptr, ws_loss);
        hipLaunchKernelGGL(kdw, dim3(1024), dim3(512), 0, stream,
                           ws_idx, ws_flat, ws_dw);
    } else {
        // fallback: verified exact path with atomic dw
        // zero hist..dw span (1024+1+1+2+65536+131072 = 197636 words)
        hipLaunchKernelGGL(kzero, dim3(773), dim3(256), 0, stream, (float*)ws_hist, 197636);
        hipLaunchKernelGGL(knx, dim3(512), dim3(256), 0, stream, ze, ws_nx, (float*)nullptr);
        hipLaunchKernelGGL(knorm, dim3(4), dim3(256), 0, stream, embed, ws_norm2,
                           (unsigned short*)nullptr, (unsigned short*)nullptr);
        hipLaunchKernelGGL(kargmin, dim3(512), dim3(256), 0, stream,
                           ze, embed, ws_norm2, ws_nx, ws_idx, out + OFF_IDX, ws_hist);
        hipLaunchKernelGGL(kquant, dim3(512), dim3(256), 0, stream,
                           ze, embed, ws_idx, out + OFF_Q, ws_dw, ws_loss);
    }
    hipLaunchKernelGGL(kfin1, dim3(1), dim3(256), 0, stream,
                       ws_hist, ema_cs, out + OFF_ECS, ws_rcp, out + OFF_LOSS, ws_loss);
    hipLaunchKernelGGL(kfin2, dim3(512), dim3(256), 0, stream,
                       ema_w, ws_dw, ws_rcp, out + OFF_EMB, out + OFF_EMAW);
}

// Round 10
// 290.720 us; speedup vs baseline: 2.3662x; 2.3662x over previous
//
#include <hip/hip_runtime.h>

#define K_CODES 1024
#define DIM 128
#define HW 1024
#define NTOT 65536
#define DECAY 0.99f
#define OMD 0.01f
#define EPS 1e-5f
#define CCOEF 0.25f
#define MARGIN 1e-4f

// d_out offsets (floats)
#define OFF_Q    0
#define OFF_IDX  8388608
#define OFF_LOSS (8388608 + 65536)
#define OFF_EMB  (OFF_LOSS + 1)
#define OFF_ECS  (OFF_EMB + 131072)
#define OFF_EMAW (OFF_ECS + 1024)

typedef __attribute__((ext_vector_type(8))) short short8v;
typedef __attribute__((ext_vector_type(4))) float f32x4;

__device__ __forceinline__ unsigned short f2bf(float f) {
    unsigned u = __float_as_uint(f);
    u += 0x7fffu + ((u >> 16) & 1u);      // RNE to bf16 (inputs finite)
    return (unsigned short)(u >> 16);
}
__device__ __forceinline__ float bf2f(unsigned short h) {
    return __uint_as_float(((unsigned)h) << 16);
}

__global__ __launch_bounds__(256) void kzero(float* __restrict__ p, int n) {
    int i = blockIdx.x * 256 + threadIdx.x;
    if (i < n) p[i] = 0.f;
}

// numpy pairwise_sum replica (contiguous fp32, n=128, SSE nlanes=4) — verified.
__device__ __forceinline__ float np_pairwise_sumsq_128(const float* p, size_t stride) {
    float r[8][4];
    #pragma unroll
    for (int j = 0; j < 8; ++j)
        #pragma unroll
        for (int L = 0; L < 4; ++L) {
            float x = p[(size_t)(j * 4 + L) * stride];
            r[j][L] = __fmul_rn(x, x);
        }
    #pragma unroll
    for (int c = 1; c < 4; ++c)
        #pragma unroll
        for (int j = 0; j < 8; ++j)
            #pragma unroll
            for (int L = 0; L < 4; ++L) {
                float x = p[(size_t)(c * 32 + j * 4 + L) * stride];
                r[j][L] = __fadd_rn(r[j][L], __fmul_rn(x, x));
            }
    float V[4];
    #pragma unroll
    for (int L = 0; L < 4; ++L) {
        float a = __fadd_rn(r[0][L], r[1][L]);
        float b = __fadd_rn(r[2][L], r[3][L]);
        float c2 = __fadd_rn(r[4][L], r[5][L]);
        float d2 = __fadd_rn(r[6][L], r[7][L]);
        V[L] = __fadd_rn(__fadd_rn(a, b), __fadd_rn(c2, d2));
    }
    return __fadd_rn(__fadd_rn(V[0], V[1]), __fadd_rn(V[2], V[3]));
}

// LDS-transpose 128 rows of ze -> flat_c (coalesced) + nx per row (verified).
__global__ __launch_bounds__(256) void knx(const float* __restrict__ ze,
                                           float* __restrict__ nx,
                                           float* __restrict__ flat_c) {
    __shared__ float t[128][133];
    const int tid = threadIdx.x;
    const int n0 = blockIdx.x * 128;
    const int b = n0 >> 10, hw0 = n0 & (HW - 1);
    const float* zb = ze + (size_t)b * (DIM * HW) + hw0;
    #pragma unroll
    for (int i = 0; i < 64; ++i) {
        int d = i * 2 + (tid >> 7);
        int hw = tid & 127;
        t[hw][d] = zb[(size_t)d * HW + hw];
    }
    __syncthreads();
    if (tid < 128) nx[n0 + tid] = np_pairwise_sumsq_128(&t[tid][0], 1);
    if (flat_c) {
        #pragma unroll
        for (int i = 0; i < 16; ++i) {
            int lin = i * 256 + tid;
            int r  = lin >> 5;
            int c4 = lin & 31;
            float4 v = *(const float4*)&t[r][c4 * 4];
            *(float4*)&flat_c[(size_t)(n0 + r) * DIM + c4 * 4] = v;
        }
    }
}

// ne[k] (np-pairwise, verified) + bf16 hi/lo split of embed
__global__ __launch_bounds__(256) void knorm(const float* __restrict__ embed,
                                             float* __restrict__ norm2,
                                             unsigned short* __restrict__ eh_g,
                                             unsigned short* __restrict__ el_g) {
    int k = blockIdx.x * 256 + threadIdx.x;
    const float* row = embed + (size_t)k * DIM;
    norm2[k] = np_pairwise_sumsq_128(row, 1);
    if (eh_g) {
        #pragma unroll 8
        for (int d = 0; d < DIM; ++d) {
            float f = row[d];
            unsigned short h = f2bf(f);
            eh_g[(size_t)k * DIM + d] = h;
            el_g[(size_t)k * DIM + d] = f2bf(f - bf2f(h));
        }
    }
}

// bf16x3 MFMA single-pass argmin (verified r9). Per row tracks (min1,code1,min2);
// gap > MARGIN proves the exact winner (skew bound ~4.7e-5 incl. tie guard);
// else row flagged for krefine's exact scan.
__global__ __launch_bounds__(256, 2) void kapprox(
    const float* __restrict__ flat_c, const unsigned short* __restrict__ eh_g,
    const unsigned short* __restrict__ el_g, const float* __restrict__ norm2,
    int* __restrict__ idx_ws, float* __restrict__ idx_out,
    unsigned* __restrict__ hist, unsigned* __restrict__ flcnt,
    unsigned* __restrict__ fl_list)
{
    __shared__ __align__(16) unsigned short ehs[2][64 * 128];
    __shared__ __align__(16) unsigned short els[2][64 * 128];
    __shared__ float nes[1024];

    const int tid = threadIdx.x;
    const int l = tid & 63;
    const int w = tid >> 6;
    const int lg = l >> 4;        // 0..3
    const int lm = l & 15;
    const int n0 = blockIdx.x * 128;

    for (int i = tid; i < 1024; i += 256) nes[i] = norm2[i];

    // x-frags: rows n0 + w*32 + lm (group0) / +16 (group1); k = ks*32+lg*8+e
    short8v xh0[4], xl0[4], xh1[4], xl1[4];
    {
        const float* xr0 = flat_c + (size_t)(n0 + w * 32 + lm) * DIM;
        const float* xr1 = xr0 + 16 * DIM;
        #pragma unroll
        for (int ks = 0; ks < 4; ++ks) {
            int kb = ks * 32 + lg * 8;
            float f0[8], f1[8];
            *(float4*)&f0[0] = *(const float4*)(xr0 + kb);
            *(float4*)&f0[4] = *(const float4*)(xr0 + kb + 4);
            *(float4*)&f1[0] = *(const float4*)(xr1 + kb);
            *(float4*)&f1[4] = *(const float4*)(xr1 + kb + 4);
            #pragma unroll
            for (int e = 0; e < 8; ++e) {
                unsigned short h0 = f2bf(f0[e]);
                unsigned short h1 = f2bf(f1[e]);
                xh0[ks][e] = (short)h0;
                xl0[ks][e] = (short)f2bf(f0[e] - bf2f(h0));
                xh1[ks][e] = (short)h1;
                xl1[ks][e] = (short)f2bf(f1[e] - bf2f(h1));
            }
        }
    }

    // staging: 4 slots/array/thread; slot j -> code (tid>>4)+j*16, granule tid&15
    const int cc = tid >> 4;
    const int g0 = tid & 15;
    int soff[4];
    size_t gsrc[4];
    #pragma unroll
    for (int j = 0; j < 4; ++j) {
        int c = cc + j * 16;
        soff[j] = c * 128 + ((g0 ^ (c & 15)) * 8);
        gsrc[j] = (size_t)c * 128 + g0 * 8;
    }

    uint4 ph[4], pl[4];
    #pragma unroll
    for (int j = 0; j < 4; ++j) {
        ph[j] = *(const uint4*)(eh_g + gsrc[j]);
        pl[j] = *(const uint4*)(el_g + gsrc[j]);
    }
    #pragma unroll
    for (int j = 0; j < 4; ++j) {
        *(uint4*)&ehs[0][soff[j]] = ph[j];
        *(uint4*)&els[0][soff[j]] = pl[j];
    }
    __syncthreads();

    float m1_0 = 3.4e38f, m2_0 = 3.4e38f;
    float m1_1 = 3.4e38f, m2_1 = 3.4e38f;
    int c1_0 = 0, c1_1 = 0;

    for (int it = 0; it < 16; ++it) {
        const int buf = it & 1;
        const int nt = it + 1;
        if (nt < 16) {
            const size_t nb = (size_t)nt * 8192;
            #pragma unroll
            for (int j = 0; j < 4; ++j) {
                ph[j] = *(const uint4*)(eh_g + nb + gsrc[j]);
                pl[j] = *(const uint4*)(el_g + nb + gsrc[j]);
            }
        }
        #pragma unroll
        for (int sub = 0; sub < 4; ++sub) {
            f32x4 a0 = {0.f,0.f,0.f,0.f}, a1 = {0.f,0.f,0.f,0.f};
            #pragma unroll
            for (int ks = 0; ks < 4; ++ks) {
                int off = sub * 2048 + lm * 128 + (((ks * 4 + lg) ^ lm) * 8);
                short8v e8 = *(const short8v*)(&ehs[buf][off]);
                short8v l8 = *(const short8v*)(&els[buf][off]);
                a0 = __builtin_amdgcn_mfma_f32_16x16x32_bf16(e8, xh0[ks], a0, 0, 0, 0);
                a0 = __builtin_amdgcn_mfma_f32_16x16x32_bf16(l8, xh0[ks], a0, 0, 0, 0);
                a0 = __builtin_amdgcn_mfma_f32_16x16x32_bf16(e8, xl0[ks], a0, 0, 0, 0);
                a1 = __builtin_amdgcn_mfma_f32_16x16x32_bf16(e8, xh1[ks], a1, 0, 0, 0);
                a1 = __builtin_amdgcn_mfma_f32_16x16x32_bf16(l8, xh1[ks], a1, 0, 0, 0);
                a1 = __builtin_amdgcn_mfma_f32_16x16x32_bf16(e8, xl1[ks], a1, 0, 0, 0);
            }
            #pragma unroll
            for (int r = 0; r < 4; ++r) {
                int code = it * 64 + sub * 16 + lg * 4 + r;
                float ne = nes[code];
                float s0 = ne - 2.f * a0[r];
                float s1 = ne - 2.f * a1[r];
                m2_0 = fminf(m2_0, fmaxf(m1_0, s0));
                if (s0 < m1_0) { m1_0 = s0; c1_0 = code; }
                m2_1 = fminf(m2_1, fmaxf(m1_1, s1));
                if (s1 < m1_1) { m1_1 = s1; c1_1 = code; }
            }
        }
        if (nt < 16) {
            #pragma unroll
            for (int j = 0; j < 4; ++j) {
                *(uint4*)&ehs[buf ^ 1][soff[j]] = ph[j];
                *(uint4*)&els[buf ^ 1][soff[j]] = pl[j];
            }
        }
        __syncthreads();
    }

    // merge (m1,c1,m2) across the 4 lg lanes (xor 16, then 32)
    #pragma unroll
    for (int mk = 16; mk <= 32; mk <<= 1) {
        float om1 = __shfl_xor(m1_0, mk, 64);
        int   oc1 = __shfl_xor(c1_0, mk, 64);
        float om2 = __shfl_xor(m2_0, mk, 64);
        m2_0 = fminf(fminf(m2_0, om2), fmaxf(m1_0, om1));
        if (om1 < m1_0 || (om1 == m1_0 && oc1 < c1_0)) { m1_0 = om1; c1_0 = oc1; }
        float pm1 = __shfl_xor(m1_1, mk, 64);
        int   pc1 = __shfl_xor(c1_1, mk, 64);
        float pm2 = __shfl_xor(m2_1, mk, 64);
        m2_1 = fminf(fminf(m2_1, pm2), fmaxf(m1_1, pm1));
        if (pm1 < m1_1 || (pm1 == m1_1 && pc1 < c1_1)) { m1_1 = pm1; c1_1 = pc1; }
    }
    if (lg == 0) {
        int n = n0 + w * 32 + lm;
        if (m2_0 - m1_0 > MARGIN) {
            idx_ws[n] = c1_0;
            idx_out[n] = (float)c1_0;
            atomicAdd(&hist[c1_0], 1u);
        } else {
            unsigned p = atomicAdd(flcnt, 1u);
            fl_list[p] = (unsigned)n;
        }
        n += 16;
        if (m2_1 - m1_1 > MARGIN) {
            idx_ws[n] = c1_1;
            idx_out[n] = (float)c1_1;
            atomicAdd(&hist[c1_1], 1u);
        } else {
            unsigned p = atomicAdd(flcnt, 1u);
            fl_list[p] = (unsigned)n;
        }
    }
}

// exact full-scan for flagged rows, v2: 16 rows/block; 16 chunks of 64 codes
// staged COALESCED into LDS; each thread computes 4 codes {q,q+16,q+32,q+48}
// (4 independent fmaf chains = 4-way ILP; LDS reads 2-way/free by layout).
// Bit-identical semantics to verified kargmin: ascending-d fmaf chain,
// s = fsub(fadd(nx,ne), fmul(2,dot)), lowest-k tie (order-independent compare).
__global__ __launch_bounds__(256) void krefine(
    const float* __restrict__ flat_c, const float* __restrict__ embed,
    const float* __restrict__ norm2, const float* __restrict__ nxg,
    const unsigned* __restrict__ flcnt, const unsigned* __restrict__ fl_list,
    int* __restrict__ idx_ws, float* __restrict__ idx_out,
    unsigned* __restrict__ hist)
{
    __shared__ float ec[64 * 132];
    __shared__ float xrow[16][132];
    __shared__ float xnx[16];
    __shared__ int   rn[16];
    const int tid = threadIdx.x;
    const int row = tid >> 4;
    const int q = tid & 15;
    const unsigned nflag = flcnt[0];
    for (unsigned base = blockIdx.x * 16u; base < nflag; base += gridDim.x * 16u) {
        __syncthreads();   // previous batch fully consumed
        if (tid < 16) {
            unsigned f = base + tid;
            int n = (f < nflag) ? (int)fl_list[f] : -1;
            rn[tid] = n;
            xnx[tid] = (n >= 0) ? nxg[n] : 0.f;
        }
        __syncthreads();
        #pragma unroll
        for (int j = 0; j < 8; ++j) {
            int slot = j * 256 + tid;      // 2048 = 16 rows x 128 d
            int r = slot >> 7, d = slot & 127;
            int n = rn[r];
            xrow[r][d] = (n >= 0) ? flat_c[(size_t)n * DIM + d] : 0.f;
        }
        float bs = 3.4e38f;
        int bk = 1 << 30;
        const int nrow = rn[row];
        const float nx = xnx[row];
        for (int chunk = 0; chunk < 16; ++chunk) {
            __syncthreads();   // xrow staged (1st iter) / prev chunk consumed
            #pragma unroll
            for (int j = 0; j < 8; ++j) {
                int lin = j * 256 + tid;   // 2048 float4 = 64 codes x 32
                int c = lin >> 5, d4 = lin & 31;
                float4 v = *(const float4*)(embed + (size_t)(chunk * 64 + c) * DIM + d4 * 4);
                *(float4*)&ec[c * 132 + d4 * 4] = v;
            }
            __syncthreads();
            #pragma unroll
            for (int jj = 0; jj < 4; ++jj) {
                int cl = q + jj * 16;
                int k = chunk * 64 + cl;
                const float* ep = &ec[cl * 132];
                const float* xp = &xrow[row][0];
                float dot = 0.f;
                #pragma unroll
                for (int d4 = 0; d4 < 32; ++d4) {
                    float4 e4 = *(const float4*)(ep + d4 * 4);
                    float4 x4 = *(const float4*)(xp + d4 * 4);
                    dot = fmaf(x4.x, e4.x, dot);
                    dot = fmaf(x4.y, e4.y, dot);
                    dot = fmaf(x4.z, e4.z, dot);
                    dot = fmaf(x4.w, e4.w, dot);
                }
                float s = __fsub_rn(__fadd_rn(nx, norm2[k]), __fmul_rn(2.f, dot));
                if (s < bs || (s == bs && k < bk)) { bs = s; bk = k; }
            }
        }
        #pragma unroll
        for (int off = 8; off >= 1; off >>= 1) {
            float os = __shfl_xor(bs, off, 16);
            int   ok = __shfl_xor(bk, off, 16);
            if (os < bs || (os == bs && ok < bk)) { bs = os; bk = ok; }
        }
        if (q == 0 && nrow >= 0) {
            idx_ws[nrow] = bk;
            idx_out[nrow] = (float)bk;
            atomicAdd(&hist[bk], 1u);
        }
    }
}

// ---- fallback exact-GEMM argmin (verified path, used when ws too small) ----
__global__ __launch_bounds__(256, 2) void kargmin(
    const float* __restrict__ ze, const float* __restrict__ embed,
    const float* __restrict__ norm2, const float* __restrict__ nxg,
    int* __restrict__ idx_ws, float* __restrict__ idx_out,
    unsigned int* __restrict__ hist)
{
    __shared__ float xs[128 * 36];
    __shared__ float es[128 * 36];
    __shared__ float nxs[128];
    const int tid = threadIdx.x;
    const int tx = tid & 15, ty = tid >> 4;
    const int n0 = blockIdx.x * 128;
    const float* zbase = ze + (size_t)(n0 >> 10) * (DIM * HW) + (n0 & (HW - 1));
    if (tid < 128) nxs[tid] = nxg[n0 + tid];
    float minv[8];
    int   mini[8];
    #pragma unroll
    for (int i = 0; i < 8; ++i) { minv[i] = 3.4e38f; mini[i] = 0; }
    for (int kt = 0; kt < 8; ++kt) {
        float acc[8][8];
        #pragma unroll
        for (int i = 0; i < 8; ++i)
            #pragma unroll
            for (int j = 0; j < 8; ++j) acc[i][j] = 0.f;
        for (int dc = 0; dc < 4; ++dc) {
            __syncthreads();
            #pragma unroll
            for (int it = 0; it < 4; ++it) {
                int lin = it * 256 + tid;
                int r  = lin & 127;
                int gu = lin >> 7;
                const float* gp = zbase + (size_t)(dc * 32 + gu * 4) * HW + r;
                float4 v;
                v.x = gp[0]; v.y = gp[HW]; v.z = gp[2 * HW]; v.w = gp[3 * HW];
                *(float4*)&xs[r * 36 + gu * 4] = v;
            }
            #pragma unroll
            for (int it = 0; it < 4; ++it) {
                int lin = it * 256 + tid;
                int k  = lin >> 3;
                int gu = lin & 7;
                float4 v = *(const float4*)(embed + (size_t)(kt * 128 + k) * DIM + dc * 32 + gu * 4);
                *(float4*)&es[k * 36 + gu * 4] = v;
            }
            __syncthreads();
            #pragma unroll
            for (int g = 0; g < 8; ++g) {
                float4 xf[8];
                #pragma unroll
                for (int i = 0; i < 8; ++i)
                    xf[i] = *(const float4*)&xs[(ty + i * 16) * 36 + g * 4];
                #pragma unroll
                for (int j = 0; j < 8; ++j) {
                    float4 ef = *(const float4*)&es[(tx + j * 16) * 36 + g * 4];
                    #pragma unroll
                    for (int i = 0; i < 8; ++i) {
                        acc[i][j] = fmaf(xf[i].x, ef.x, acc[i][j]);
                        acc[i][j] = fmaf(xf[i].y, ef.y, acc[i][j]);
                        acc[i][j] = fmaf(xf[i].z, ef.z, acc[i][j]);
                        acc[i][j] = fmaf(xf[i].w, ef.w, acc[i][j]);
                    }
                }
            }
        }
        #pragma unroll
        for (int j = 0; j < 8; ++j) {
            int kg = kt * 128 + tx + j * 16;
            float nrm = norm2[kg];
            #pragma unroll
            for (int i = 0; i < 8; ++i) {
                float q = __fadd_rn(nxs[ty + i * 16], nrm);
                float t = __fmul_rn(2.f, acc[i][j]);
                float s = __fsub_rn(q, t);
                if (s < minv[i]) { minv[i] = s; mini[i] = kg; }
            }
        }
    }
    #pragma unroll
    for (int i = 0; i < 8; ++i) {
        float v = minv[i]; int ix = mini[i];
        #pragma unroll
        for (int off = 8; off >= 1; off >>= 1) {
            float v2 = __shfl_xor(v, off, 16);
            int   i2 = __shfl_xor(ix, off, 16);
            if (v2 < v || (v2 == v && i2 < ix)) { v = v2; ix = i2; }
        }
        if (tx == 0) {
            int n = n0 + ty + i * 16;
            idx_ws[n] = ix;
            idx_out[n] = (float)ix;
            atomicAdd(&hist[ix], 1u);
        }
    }
}

// gather quantized, transposed write, loss (+ optional atomic dw fallback)
__global__ __launch_bounds__(256) void kquant(
    const float* __restrict__ ze, const float* __restrict__ embed,
    const int* __restrict__ idx_ws, float* __restrict__ qout,
    float* __restrict__ dw_atomic, float* __restrict__ loss_acc)
{
    __shared__ float q[128 * 133];
    __shared__ int idxs[128];
    __shared__ float lsum[4];
    const int tid = threadIdx.x;
    const int n0 = blockIdx.x * 128;
    const int b = n0 >> 10;
    const int hw0 = n0 & (HW - 1);
    if (tid < 128) idxs[tid] = idx_ws[n0 + tid];
    __syncthreads();
    #pragma unroll
    for (int it = 0; it < 16; ++it) {
        int r = it * 8 + (tid >> 5);
        int c = tid & 31;
        float4 v = *(const float4*)(embed + (size_t)idxs[r] * DIM + c * 4);
        *(float4*)&q[r * 133 + c * 4] = v;
    }
    __syncthreads();
    const float* zb = ze + (size_t)b * (DIM * HW) + hw0;
    float* qb = qout + (size_t)b * (DIM * HW) + hw0;
    float lacc = 0.f;
    for (int dd = 0; dd < 64; ++dd) {
        int d = dd * 2 + (tid >> 7);
        int hw = tid & 127;
        float val = q[hw * 133 + d];
        size_t off = (size_t)d * HW + hw;
        float z = zb[off];
        qb[off] = val;
        float diff = val - z;
        lacc = fmaf(diff, diff, lacc);
        if (dw_atomic) atomicAdd(&dw_atomic[idxs[hw] * DIM + d], z);
    }
    #pragma unroll
    for (int off = 32; off >= 1; off >>= 1) lacc += __shfl_xor(lacc, off, 64);
    if ((tid & 63) == 0) lsum[tid >> 6] = lacc;
    __syncthreads();
    if (tid == 0) atomicAdd(loss_acc, lsum[0] + lsum[1] + lsum[2] + lsum[3]);
}

// deterministic segment-sum: block(8 waves)/code, waves scan n-ranges ascending
__global__ __launch_bounds__(512) void kdw(
    const int* __restrict__ idx_ws, const float* __restrict__ flat_c,
    float* __restrict__ dw)
{
    __shared__ float part[8][128];
    const int k = blockIdx.x;
    const int lane = threadIdx.x & 63;
    const int w = threadIdx.x >> 6;
    float lo = 0.f, hi = 0.f;
    const int nbeg = w * (NTOT / 8);
    const int nend = nbeg + (NTOT / 8);
    for (int base = nbeg; base < nend; base += 64) {
        int my = idx_ws[base + lane];
        unsigned long long m = __ballot(my == k);
        while (m) {
            int bit = __ffsll((long long)m) - 1;
            m &= m - 1;
            const float* row = flat_c + (size_t)(base + bit) * DIM;
            lo += row[lane];
            hi += row[lane + 64];
        }
    }
    part[w][lane] = lo;
    part[w][lane + 64] = hi;
    __syncthreads();
    if (w == 0) {
        float a = part[0][lane], b = part[0][lane + 64];
        #pragma unroll
        for (int u = 1; u < 8; ++u) {
            a += part[u][lane];
            b += part[u][lane + 64];
        }
        dw[k * DIM + lane] = a;
        dw[k * DIM + lane + 64] = b;
    }
}

__global__ __launch_bounds__(256) void kfin1(
    const unsigned int* __restrict__ hist, const float* __restrict__ ema_cs,
    float* __restrict__ out_ecs, float* __restrict__ rcp,
    float* __restrict__ loss_out, const float* __restrict__ loss_acc)
{
    const int tid = threadIdx.x;
    __shared__ float wsum[4];
    float local = 0.f;
    float necs[4];
    #pragma unroll
    for (int u = 0; u < 4; ++u) {
        int k = u * 256 + tid;
        necs[u] = DECAY * ema_cs[k] + OMD * (float)hist[k];
        out_ecs[k] = necs[u];
        local += necs[u];
    }
    #pragma unroll
    for (int off = 32; off >= 1; off >>= 1) local += __shfl_xor(local, off, 64);
    if ((tid & 63) == 0) wsum[tid >> 6] = local;
    __syncthreads();
    float ntot = wsum[0] + wsum[1] + wsum[2] + wsum[3];
    #pragma unroll
    for (int u = 0; u < 4; ++u) {
        int k = u * 256 + tid;
        float cs = (necs[u] + EPS) / (ntot + (float)K_CODES * EPS) * ntot;
        rcp[k] = 1.f / cs;
    }
    if (tid == 0) loss_out[0] = loss_acc[0] * (CCOEF / (float)((size_t)NTOT * DIM));
}

__global__ __launch_bounds__(256) void kfin2(
    const float* __restrict__ ema_w, const float* __restrict__ dw,
    const float* __restrict__ rcp, float* __restrict__ out_emb,
    float* __restrict__ out_emaw)
{
    int e = blockIdx.x * 256 + threadIdx.x;
    int k = e >> 7;
    float nw = DECAY * ema_w[e] + OMD * dw[e];
    out_emaw[e] = nw;
    out_emb[e] = nw * rcp[k];
}

extern "C" void kernel_launch(void* const* d_in, const int* in_sizes, int n_in,
                              void* d_out, int out_size, void* d_ws, size_t ws_size,
                              hipStream_t stream) {
    const float* ze     = (const float*)d_in[0];
    const float* embed  = (const float*)d_in[1];
    const float* ema_cs = (const float*)d_in[2];
    const float* ema_w  = (const float*)d_in[3];
    float* out = (float*)d_out;

    // ws layout (words), NO aliases (kapprox writes idx while eh still live):
    // hist/loss/flcnt/fl_list/dw contiguous so one kzero covers accumulators.
    float* ws = (float*)d_ws;
    float*          ws_norm2 = ws;                                   // 1024
    float*          ws_rcp   = ws + 1024;                            // 1024
    int*            ws_idx   = (int*)(ws + 2048);                    // 65536
    unsigned*       ws_hist  = (unsigned*)(ws + 67584);              // 1024
    float*          ws_loss  = ws + 68608;                           // 1
    unsigned*       ws_flcnt = (unsigned*)(ws + 68609);              // 1 (+2 pad)
    unsigned*       ws_fl    = (unsigned*)(ws + 68612);              // 65536
    float*          ws_dw    = ws + 134148;                          // 131072
    unsigned short* ws_eh    = (unsigned short*)(ws + 265220);       // 65536 words
    unsigned short* ws_el    = (unsigned short*)(ws + 330756);       // 65536 words
    float*          ws_nx    = ws + 396292;                          // 65536
    float*          ws_flat  = ws + 461828;                          // 8388608
    const size_t need = (size_t)8850436 * sizeof(float);
    const bool big_ws = ws_size >= need;

    if (big_ws) {
        // zero hist + loss + flcnt (contiguous 1026 words)
        hipLaunchKernelGGL(kzero, dim3(5), dim3(256), 0, stream, (float*)ws_hist, 1026);
        hipLaunchKernelGGL(knx, dim3(512), dim3(256), 0, stream, ze, ws_nx, ws_flat);
        hipLaunchKernelGGL(knorm, dim3(4), dim3(256), 0, stream, embed, ws_norm2, ws_eh, ws_el);
        hipLaunchKernelGGL(kapprox, dim3(512), dim3(256), 0, stream,
                           ws_flat, ws_eh, ws_el, ws_norm2,
                           ws_idx, out + OFF_IDX, ws_hist, ws_flcnt, ws_fl);
        hipLaunchKernelGGL(krefine, dim3(512), dim3(256), 0, stream,
                           ws_flat, embed, ws_norm2, ws_nx, ws_flcnt, ws_fl,
                           ws_idx, out + OFF_IDX, ws_hist);
        hipLaunchKernelGGL(kquant, dim3(512), dim3(256), 0, stream,
                           ze, embed, ws_idx, out + OFF_Q, (float*)nullptr, ws_loss);
        hipLaunchKernelGGL(kdw, dim3(1024), dim3(512), 0, stream,
                           ws_idx, ws_flat, ws_dw);
    } else {
        // fallback: verified exact path with atomic dw
        // zero hist..dw span (1024+1+1+2+65536+131072 = 197636 words)
        hipLaunchKernelGGL(kzero, dim3(773), dim3(256), 0, stream, (float*)ws_hist, 197636);
        hipLaunchKernelGGL(knx, dim3(512), dim3(256), 0, stream, ze, ws_nx, (float*)nullptr);
        hipLaunchKernelGGL(knorm, dim3(4), dim3(256), 0, stream, embed, ws_norm2,
                           (unsigned short*)nullptr, (unsigned short*)nullptr);
        hipLaunchKernelGGL(kargmin, dim3(512), dim3(256), 0, stream,
                           ze, embed, ws_norm2, ws_nx, ws_idx, out + OFF_IDX, ws_hist);
        hipLaunchKernelGGL(kquant, dim3(512), dim3(256), 0, stream,
                           ze, embed, ws_idx, out + OFF_Q, ws_dw, ws_loss);
    }
    hipLaunchKernelGGL(kfin1, dim3(1), dim3(256), 0, stream,
                       ws_hist, ema_cs, out + OFF_ECS, ws_rcp, out + OFF_LOSS, ws_loss);
    hipLaunchKernelGGL(kfin2, dim3(512), dim3(256), 0, stream,
                       ema_w, ws_dw, ws_rcp, out + OFF_EMB, out + OFF_EMAW);
}